// Round 8
// baseline (314.160 us; speedup 1.0000x reference)
//
#include <hip/hip_runtime.h>
#include <hip/hip_bf16.h>
#include <cstdint>
#include <math.h>

#define DEVINL __device__ __forceinline__

typedef __attribute__((ext_vector_type(8))) __bf16 bf16x8;
typedef __attribute__((ext_vector_type(4))) float floatx4;
typedef __attribute__((ext_vector_type(4))) int intx4;

constexpr int TB = 2;        // batch
constexpr int TT = 2048;     // seq len
constexpr int TC = 2048;     // channels
constexpr int NH = 16, NKV = 4, HD = 128;
constexpr int MR = TB * TT;           // 4096 token rows
constexpr int NQ = NH * HD;           // 2048
constexpr int NK = NKV * HD;          // 512
constexpr int NQKV = NQ + 2 * NK;     // 3072

// ---------- helpers ----------
DEVINL unsigned bfbits(float f) {  // fp32 -> bf16 bits, RNE
  unsigned u = __builtin_bit_cast(unsigned, f);
  return (u + 0x7FFFu + ((u >> 16) & 1u)) >> 16;
}
DEVINL int pk2(float a, float b) {  // packed fp32x2 -> bf16x2 (v_cvt_pk_bf16_f32)
  union { __hip_bfloat162 h; int i; } u;
  u.h = __float22bfloat162_rn(float2{a, b});
  return u.i;
}
DEVINL void gl_lds16(const __hip_bfloat16* g, __hip_bfloat16* l) {
  __builtin_amdgcn_global_load_lds(
      (const __attribute__((address_space(1))) unsigned int*)g,
      (__attribute__((address_space(3))) unsigned int*)l, 16, 0, 0);
}
DEVINL floatx4 mfma16(bf16x8 a, bf16x8 b, floatx4 c) {
  return __builtin_amdgcn_mfma_f32_16x16x32_bf16(a, b, c, 0, 0, 0);
}
DEVINL void cstore(float* p, float v) { *p = v; }
DEVINL void cstore(__hip_bfloat16* p, float v) { *(unsigned short*)p = (unsigned short)bfbits(v); }
DEVINL void bar() {  // raw s_barrier with compiler memory fences (no waitcnt drain)
  asm volatile("" ::: "memory");
  __builtin_amdgcn_s_barrier();
  asm volatile("" ::: "memory");
}

// ---------- fused fp32 -> bf16 convert (all 5 inputs, one launch) ----------
__global__ __launch_bounds__(256) void k_cvt5(
    const float* __restrict__ s0, const float* __restrict__ s1,
    const float* __restrict__ s2, const float* __restrict__ s3,
    const float* __restrict__ s4,
    __hip_bfloat16* __restrict__ d0, __hip_bfloat16* __restrict__ d1,
    __hip_bfloat16* __restrict__ d2, __hip_bfloat16* __restrict__ d3,
    __hip_bfloat16* __restrict__ d4) {
  const float* s;
  __hip_bfloat16* d;
  int n;
  switch (blockIdx.y) {
    case 0: s = s0; d = d0; n = MR * TC; break;
    case 1: s = s1; d = d1; n = NQ * TC; break;
    case 2: s = s2; d = d2; n = NK * TC; break;
    case 3: s = s3; d = d3; n = NK * TC; break;
    default: s = s4; d = d4; n = TC * TC; break;
  }
  int i = (blockIdx.x * 256 + threadIdx.x) * 4;
  if (i >= n) return;
  float4 v = *(const float4*)(s + i);
  ushort4 o;
  o.x = (unsigned short)bfbits(v.x);
  o.y = (unsigned short)bfbits(v.y);
  o.z = (unsigned short)bfbits(v.z);
  o.w = (unsigned short)bfbits(v.w);
  *(ushort4*)(d + i) = o;
}

// ---------- GEMM 256x256, 4-phase-per-tile counted-vmcnt pipeline ----------
// (verified R6/R7). Used for GEMM1: grid 12x16 = 192 blocks.
__global__ __launch_bounds__(512, 1) void k_gemm256(
    const __hip_bfloat16* __restrict__ A, const __hip_bfloat16* __restrict__ B,
    __hip_bfloat16* __restrict__ C, int M, int N, int K) {
  __shared__ __align__(16) __hip_bfloat16 As[2][256 * 64];  // 64 KB
  __shared__ __align__(16) __hip_bfloat16 Bs[2][256 * 64];  // 64 KB
  const int tid = threadIdx.x;
  const int lane = tid & 63, w = tid >> 6;
  const int q15 = lane & 15, quad = lane >> 4;
  const int wm = w >> 2, wn = w & 3;
  const int tm = blockIdx.y, tn = blockIdx.x;

  const int r0 = tid >> 3;
  const int csw = ((tid & 7) ^ (r0 & 7)) * 8;
  const __hip_bfloat16* ag = A + (size_t)(tm * 256 + r0) * K + csw;
  const __hip_bfloat16* bg = B + (size_t)(tn * 256 + r0) * K + csw;
  const int ldst = (tid & ~63) * 8;

  auto stA = [&](int kt, int buf, int c) {
    gl_lds16(ag + (size_t)(c * 64) * K + kt * 64, &As[buf][c * 4096 + ldst]);
  };
  auto stB = [&](int kt, int buf, int c) {
    gl_lds16(bg + (size_t)(c * 64) * K + kt * 64, &Bs[buf][c * 4096 + ldst]);
  };

  floatx4 acc[8][4] = {};
  bf16x8 af[4][2], bfr[4][2];
  const int NT = K / 64;
  const int rsw = q15 & 7;

  auto quad_mfma = [&](int mh, int nh) {
    __builtin_amdgcn_s_setprio(1);
#pragma unroll
    for (int mi = 0; mi < 4; ++mi)
#pragma unroll
      for (int ni = 0; ni < 2; ++ni)
#pragma unroll
        for (int kh = 0; kh < 2; ++kh)
          acc[mh * 4 + mi][nh * 2 + ni] =
              mfma16(af[mi][kh], bfr[nh * 2 + ni][kh], acc[mh * 4 + mi][nh * 2 + ni]);
    __builtin_amdgcn_s_setprio(0);
  };

  // prologue: tile0 full, tile1 {B all, A ch0,1}; wait tile0 (6 in flight)
#pragma unroll
  for (int c = 0; c < 4; ++c) { stA(0, 0, c); stB(0, 0, c); }
#pragma unroll
  for (int c = 0; c < 4; ++c) stB(1, 1, c);
  stA(1, 1, 0);
  stA(1, 1, 1);
  asm volatile("s_waitcnt vmcnt(6)" ::: "memory");
  bar();

  for (int t = 0; t < NT; ++t) {
    const int cur = t & 1;
    // ---- phase 1: read af[0..3], bfr[0,1]; stage A(t+1) ch2,3 (other buf)
#pragma unroll
    for (int i = 0; i < 4; ++i)
#pragma unroll
      for (int kh = 0; kh < 2; ++kh)
        af[i][kh] = *(const bf16x8*)&As[cur][(wm * 128 + i * 16 + q15) * 64 +
                                            ((kh * 4 + quad) ^ rsw) * 8];
#pragma unroll
    for (int n = 0; n < 2; ++n)
#pragma unroll
      for (int kh = 0; kh < 2; ++kh)
        bfr[n][kh] = *(const bf16x8*)&Bs[cur][(wn * 64 + n * 16 + q15) * 64 +
                                             ((kh * 4 + quad) ^ rsw) * 8];
    if (t + 1 < NT) { stA(t + 1, cur ^ 1, 2); stA(t + 1, cur ^ 1, 3); }
    bar();
    quad_mfma(0, 0);
    bar();
    // ---- phase 2: read bfr[2,3]; no stage
#pragma unroll
    for (int n = 2; n < 4; ++n)
#pragma unroll
      for (int kh = 0; kh < 2; ++kh)
        bfr[n][kh] = *(const bf16x8*)&Bs[cur][(wn * 64 + n * 16 + q15) * 64 +
                                             ((kh * 4 + quad) ^ rsw) * 8];
    bar();
    quad_mfma(0, 1);
    bar();
    // ---- phase 3: read af[4..7]; stage B(t+2) ch0,1 (current buf, B(t) done)
#pragma unroll
    for (int i = 0; i < 4; ++i)
#pragma unroll
      for (int kh = 0; kh < 2; ++kh)
        af[i][kh] = *(const bf16x8*)&As[cur][(wm * 128 + (i + 4) * 16 + q15) * 64 +
                                            ((kh * 4 + quad) ^ rsw) * 8];
    if (t + 2 < NT) { stB(t + 2, cur, 0); stB(t + 2, cur, 1); }
    bar();
    quad_mfma(1, 0);
    bar();
    // ---- phase 4: no reads; stage B(t+2) ch2,3 + A(t+2) ch0,1; counted vmcnt
    if (t + 2 < NT) {
      stB(t + 2, cur, 2);
      stB(t + 2, cur, 3);
      stA(t + 2, cur, 0);
      stA(t + 2, cur, 1);
      asm volatile("s_waitcnt vmcnt(6)" ::: "memory");  // tile t+1 fully landed
    } else if (t + 1 < NT) {
      asm volatile("s_waitcnt vmcnt(0)" ::: "memory");  // tail: drain t+1
    }
    bar();
    quad_mfma(1, 1);
    bar();
  }

  // epilogue
#pragma unroll
  for (int mi = 0; mi < 8; ++mi) {
    int row0 = tm * 256 + wm * 128 + mi * 16 + quad * 4;
#pragma unroll
    for (int ni = 0; ni < 4; ++ni) {
      int col = tn * 256 + wn * 64 + ni * 16 + q15;
#pragma unroll
      for (int r = 0; r < 4; ++r)
        cstore(C + (size_t)(row0 + r) * N + col, acc[mi][ni][r]);
    }
  }
}

// ---------- GEMM 256x128, 2-phase-per-tile counted-vmcnt pipeline ----------
// (verified R7). For GEMM2: grid 16x16 = 256 blocks = exact full fill at 1/CU.
__global__ __launch_bounds__(512, 1) void k_gemm2n(
    const __hip_bfloat16* __restrict__ A, const __hip_bfloat16* __restrict__ B,
    float* __restrict__ C, int M, int N, int K) {
  __shared__ __align__(16) __hip_bfloat16 As[2][256 * 64];  // 64 KB
  __shared__ __align__(16) __hip_bfloat16 Bs[2][128 * 64];  // 32 KB
  const int tid = threadIdx.x;
  const int lane = tid & 63, w = tid >> 6;
  const int q15 = lane & 15, quad = lane >> 4;
  const int wm = w >> 2, wn = w & 3;
  const int tm = blockIdx.y, tn = blockIdx.x;

  const int r0 = tid >> 3;
  const int csw = ((tid & 7) ^ (r0 & 7)) * 8;
  const __hip_bfloat16* ag = A + (size_t)(tm * 256 + r0) * K + csw;
  const __hip_bfloat16* bg = B + (size_t)(tn * 128 + r0) * K + csw;
  const int ldst = (tid & ~63) * 8;

  auto stA = [&](int kt, int buf, int c) {
    gl_lds16(ag + (size_t)(c * 64) * K + kt * 64, &As[buf][c * 4096 + ldst]);
  };
  auto stB = [&](int kt, int buf, int c) {
    gl_lds16(bg + (size_t)(c * 64) * K + kt * 64, &Bs[buf][c * 4096 + ldst]);
  };

  floatx4 acc[8][2] = {};
  bf16x8 af[4][2], bfr[2][2];
  const int NT = K / 64;
  const int rsw = q15 & 7;

  auto half_mfma = [&](int mh) {
    __builtin_amdgcn_s_setprio(1);
#pragma unroll
    for (int mi = 0; mi < 4; ++mi)
#pragma unroll
      for (int ni = 0; ni < 2; ++ni)
#pragma unroll
        for (int kh = 0; kh < 2; ++kh)
          acc[mh * 4 + mi][ni] =
              mfma16(af[mi][kh], bfr[ni][kh], acc[mh * 4 + mi][ni]);
    __builtin_amdgcn_s_setprio(0);
  };

  // prologue: t0 full (6); t1 {A ch0,2; B ch0,1} (4); wait t0
  stA(0, 0, 0); stA(0, 0, 1); stA(0, 0, 2); stA(0, 0, 3);
  stB(0, 0, 0); stB(0, 0, 1);
  stA(1, 1, 0); stA(1, 1, 2);
  stB(1, 1, 0); stB(1, 1, 1);
  asm volatile("s_waitcnt vmcnt(4)" ::: "memory");
  bar();

  for (int t = 0; t < NT; ++t) {
    const int cur = t & 1;
    // ---- phase 1: read af[0..3] + bfr; stage A(t+1) ch1,3 (other buf)
#pragma unroll
    for (int i = 0; i < 4; ++i)
#pragma unroll
      for (int kh = 0; kh < 2; ++kh)
        af[i][kh] = *(const bf16x8*)&As[cur][(wm * 128 + i * 16 + q15) * 64 +
                                            ((kh * 4 + quad) ^ rsw) * 8];
#pragma unroll
    for (int n = 0; n < 2; ++n)
#pragma unroll
      for (int kh = 0; kh < 2; ++kh)
        bfr[n][kh] = *(const bf16x8*)&Bs[cur][(wn * 32 + n * 16 + q15) * 64 +
                                             ((kh * 4 + quad) ^ rsw) * 8];
    if (t + 1 < NT) { stA(t + 1, cur ^ 1, 1); stA(t + 1, cur ^ 1, 3); }
    bar();
    half_mfma(0);
    bar();
    // ---- phase 2: read af[4..7]; stage A(t+2) ch0,2 + B(t+2) ch0,1; vmcnt
#pragma unroll
    for (int i = 0; i < 4; ++i)
#pragma unroll
      for (int kh = 0; kh < 2; ++kh)
        af[i][kh] = *(const bf16x8*)&As[cur][(wm * 128 + (i + 4) * 16 + q15) * 64 +
                                            ((kh * 4 + quad) ^ rsw) * 8];
    if (t + 2 < NT) {
      stA(t + 2, cur, 0); stA(t + 2, cur, 2);
      stB(t + 2, cur, 0); stB(t + 2, cur, 1);
      asm volatile("s_waitcnt vmcnt(4)" ::: "memory");  // tile t+1 fully landed
    } else if (t + 1 < NT) {
      asm volatile("s_waitcnt vmcnt(0)" ::: "memory");  // tail: drain t+1
    }
    bar();
    half_mfma(1);
    bar();
  }

  // epilogue
#pragma unroll
  for (int mi = 0; mi < 8; ++mi) {
    int row0 = tm * 256 + wm * 128 + mi * 16 + quad * 4;
#pragma unroll
    for (int ni = 0; ni < 2; ++ni) {
      int col = tn * 128 + wn * 32 + ni * 16 + q15;
#pragma unroll
      for (int r = 0; r < 4; ++r)
        cstore(C + (size_t)(row0 + r) * N + col, acc[mi][ni][r]);
    }
  }
}

// ---------- fused (RMSNorm + RoPE + layout) and V-transpose, one launch ----------
constexpr int ROPE_BLOCKS = (MR * 20) / 4;  // 20480
__global__ __launch_bounds__(256) void k_prep(
    const __hip_bfloat16* __restrict__ qkv,
    __hip_bfloat16* __restrict__ q_l, __hip_bfloat16* __restrict__ k_l,
    __hip_bfloat16* __restrict__ vt) {
  if (blockIdx.x < ROPE_BLOCKS) {
    int gw = (blockIdx.x * 256 + threadIdx.x) >> 6;
    int lane = threadIdx.x & 63;
    int head = gw % 20;
    int bt = gw / 20;
    int b = bt >> 11, t = bt & (TT - 1);
    bool isq = head < NH;
    int h = isq ? head : head - NH;
    const __hip_bfloat16* src = qkv + (size_t)bt * NQKV + (isq ? h * HD : NQ + h * HD);
    float x1 = __bfloat162float(src[lane]);
    float x2 = __bfloat162float(src[lane + 64]);
    float ss = x1 * x1 + x2 * x2;
#pragma unroll
    for (int m = 1; m < 64; m <<= 1) ss += __shfl_xor(ss, m, 64);
    float rinv = rsqrtf(ss * (1.0f / 128.0f) + 1.1920928955078125e-07f);
    float ang = (float)t * exp2f((float)lane * -(13.287712379549449f / 64.0f));
    float sv = sinf(ang), cv = cosf(ang);
    float scale = isq ? (1.4426950408889634f * 0.08838834764831845f) : 1.0f;
    float o1 = (x1 * cv + x2 * sv) * rinv * scale;
    float o2 = (x2 * cv - x1 * sv) * rinv * scale;
    __hip_bfloat16* dst = isq ? q_l + ((size_t)(b * NH + h) * TT + t) * HD
                              : k_l + ((size_t)(b * NKV + h) * TT + t) * HD;
    *(unsigned short*)(dst + lane) = (unsigned short)bfbits(o1);
    *(unsigned short*)(dst + lane + 64) = (unsigned short)bfbits(o2);
  } else {
    __shared__ __hip_bfloat16 tile[64][130];
    int bid = blockIdx.x - ROPE_BLOCKS;
    int t0 = (bid & 31) * 64;
    int hk = (bid >> 5) & 3;
    int b = bid >> 7;
    int tid = threadIdx.x;
#pragma unroll
    for (int j = 0; j < 32; j++) {
      int e = j * 256 + tid;
      int tt = e >> 7, d = e & 127;
      tile[tt][d] = qkv[(size_t)(b * TT + t0 + tt) * NQKV + NQ + NK + hk * HD + d];
    }
    __syncthreads();
#pragma unroll
    for (int j = 0; j < 32; j++) {
      int e = j * 256 + tid;
      int d = e >> 6, tt = e & 63;
      vt[(((size_t)(b * NKV + hk)) * HD + d) * TT + t0 + tt] = tile[tt][d];
    }
  }
}

// ---------- flash attention v8 (causal, GQA) ----------
// v4b structure with the P LDS round-trip replaced by in-register permlane
// transport: C-layout P (k in quad*4+r) -> B-operand layout (k in quad*8+j)
// via permlane32_swap + permlane16_swap per kt-pair. Rows: swap32(A_t0,A_t1)
// = [r0r1|R0R1],[r2r3|R2R3]; swap16 interleaves odd rows -> w0=[A_t0.r0,
// A_t0.r2, A_t1.r0, A_t1.r2] = exactly B-frag dword 0 (verified against the
// old validated LDS-path k/q mapping; permlane32 semantics HW-validated in
// R1's passing v5). Deletes Ps (LDS 80->64 KB), removes 8 ds_write + 8
// ds_read + lgkm join from the per-iteration critical path.
__global__ __launch_bounds__(256, 2) void k_attn(
    const __hip_bfloat16* __restrict__ q_l, const __hip_bfloat16* __restrict__ k_l,
    const __hip_bfloat16* __restrict__ vt_l, __hip_bfloat16* __restrict__ y) {
  __shared__ __align__(16) __hip_bfloat16 Ks[2][64 * 128];   // 32 KB
  __shared__ __align__(16) __hip_bfloat16 Vs[2][128 * 64];   // 32 KB
  const int tid = threadIdx.x, lane = tid & 63, w = tid >> 6;
  const int q15 = lane & 15, quad = lane >> 4;
  const int id = blockIdx.x;
  const int sl = id >> 5;  // 16 slots of 32 blocks
  const int qt = (sl < 8) ? (15 - sl) : (sl - 8);  // pair-balanced mapping
  const int h = id & 15, b = (id >> 4) & 1;
  const int hk = h >> 2;
  const int nkb = 2 * qt + 2;

  const __hip_bfloat16* kbase = k_l + (size_t)(b * NKV + hk) * TT * HD;
  const __hip_bfloat16* vbase = vt_l + (size_t)(b * NKV + hk) * HD * TT;
  const __hip_bfloat16* qbase = q_l + ((size_t)(b * NH + h) * TT + qt * 128) * HD;

  auto stage = [&](int kb, int buf) {
#pragma unroll
    for (int i = 0; i < 4; i++) {
      int s = i * 256 + tid;
      int rk = s >> 4, ck = s & 15;
      gl_lds16(kbase + (size_t)(kb * 64 + rk) * HD + (ck ^ (rk & 15)) * 8,
               Ks[buf] + (i * 256 + (tid & ~63)) * 8);
      int rv = s >> 3, cv = s & 7;
      gl_lds16(vbase + (size_t)rv * TT + kb * 64 + (cv ^ (rv & 7)) * 8,
               Vs[buf] + (i * 256 + (tid & ~63)) * 8);
    }
  };

  // Q frags: wave covers q rows qt*128 + w*32 + qh*16 + q15
  bf16x8 qf[4][2];
#pragma unroll
  for (int dc = 0; dc < 4; dc++)
#pragma unroll
    for (int qh = 0; qh < 2; qh++)
      qf[dc][qh] = *(const bf16x8*)(qbase + (size_t)(w * 32 + qh * 16 + q15) * HD +
                                    dc * 32 + quad * 8);

  floatx4 ot[8][2] = {};
  float lsum[2] = {0.0f, 0.0f};
  int cur = 0;
  const int kb_last_w = 2 * qt + (w >> 1);  // waves 0,1 skip final all-masked iter

  for (int kb = 0; kb < nkb; kb++) {
    __syncthreads();
    if (kb == 0) {
      stage(0, cur);
      __syncthreads();
    }
    if (kb + 1 < nkb) stage(kb + 1, cur ^ 1);

    if (kb <= kb_last_w) {
      // S^T = K @ Q^T : [64 k][32 q] as two 16-col C-tiles per kt
      floatx4 st[4][2] = {};
#pragma unroll
      for (int kt = 0; kt < 4; kt++) {
        int r = kt * 16 + q15;
#pragma unroll
        for (int dc = 0; dc < 4; dc++) {
          int c = dc * 4 + quad;
          bf16x8 kf = *(const bf16x8*)(Ks[cur] + (r * 16 + (c ^ (r & 15))) * 8);
          st[kt][0] = mfma16(kf, qf[dc][0], st[kt][0]);
          st[kt][1] = mfma16(kf, qf[dc][1], st[kt][1]);
        }
      }
      if (kb >= 2 * qt) {  // causal mask (diagonal region)
#pragma unroll
        for (int qh = 0; qh < 2; qh++) {
          int qg = qt * 128 + w * 32 + qh * 16 + q15;
#pragma unroll
          for (int kt = 0; kt < 4; kt++)
#pragma unroll
            for (int r = 0; r < 4; r++)
              if (kb * 64 + kt * 16 + quad * 4 + r > qg) st[kt][qh][r] = -INFINITY;
        }
      }
      // static-max softmax: p = exp2(s); pack P into per-kt dwords (C layout)
      int pA[2][4], pB[2][4];  // [qh][kt]: d0 = P(k+0,k+1), d1 = P(k+2,k+3)
#pragma unroll
      for (int kt = 0; kt < 4; kt++) {
#pragma unroll
        for (int qh = 0; qh < 2; qh++) {
          float p0 = exp2f(st[kt][qh][0]);
          float p1 = exp2f(st[kt][qh][1]);
          float p2 = exp2f(st[kt][qh][2]);
          float p3 = exp2f(st[kt][qh][3]);
          lsum[qh] += (p0 + p1) + (p2 + p3);
          pA[qh][kt] = pk2(p0, p1);
          pB[qh][kt] = pk2(p2, p3);
        }
      }
      // PV: y^T[128 d][32 q] += V^T @ P^T ; P B-frags built via permlane swaps
#pragma unroll
      for (int kc = 0; kc < 2; kc++) {
        bf16x8 pf[2];
#pragma unroll
        for (int qh = 0; qh < 2; qh++) {
          int u0 = pA[qh][2 * kc], u1 = pA[qh][2 * kc + 1];
          int v0 = pB[qh][2 * kc], v1 = pB[qh][2 * kc + 1];
          asm("v_permlane32_swap_b32 %0, %1" : "+v"(u0), "+v"(u1));
          asm("v_permlane16_swap_b32 %0, %1" : "+v"(u0), "+v"(u1));
          asm("v_permlane32_swap_b32 %0, %1" : "+v"(v0), "+v"(v1));
          asm("v_permlane16_swap_b32 %0, %1" : "+v"(v0), "+v"(v1));
          intx4 wi;
          wi[0] = u0; wi[1] = v0; wi[2] = u1; wi[3] = v1;
          pf[qh] = __builtin_bit_cast(bf16x8, wi);
        }
#pragma unroll
        for (int dt = 0; dt < 8; dt++) {
          int r = dt * 16 + q15, c = kc * 4 + quad;
          bf16x8 vf = *(const bf16x8*)(Vs[cur] + (r * 8 + (c ^ (r & 7))) * 8);
          ot[dt][0] = mfma16(vf, pf[0], ot[dt][0]);
          ot[dt][1] = mfma16(vf, pf[1], ot[dt][1]);
        }
      }
    }
    cur ^= 1;
  }
  // epilogue: reduce l across quads, normalize, store y[b][t][h*128+d]
#pragma unroll
  for (int qh = 0; qh < 2; qh++) {
    float ls = lsum[qh];
    ls += __shfl_xor(ls, 16, 64);
    ls += __shfl_xor(ls, 32, 64);
    float linv = 1.0f / ls;
    int t = qt * 128 + w * 32 + qh * 16 + q15;
    __hip_bfloat16* yrow = y + (size_t)(b * TT + t) * TC + h * HD;
#pragma unroll
    for (int dt = 0; dt < 8; dt++) {
      int d = dt * 16 + quad * 4;
      ushort4 o;
      o.x = (unsigned short)bfbits(ot[dt][qh][0] * linv);
      o.y = (unsigned short)bfbits(ot[dt][qh][1] * linv);
      o.z = (unsigned short)bfbits(ot[dt][qh][2] * linv);
      o.w = (unsigned short)bfbits(ot[dt][qh][3] * linv);
      *(ushort4*)(yrow + d) = o;
    }
  }
}

// ---------- launcher ----------
extern "C" void kernel_launch(void* const* d_in, const int* in_sizes, int n_in,
                              void* d_out, int out_size, void* d_ws, size_t ws_size,
                              hipStream_t stream) {
  (void)in_sizes; (void)n_in; (void)out_size; (void)ws_size;
  const float* x  = (const float*)d_in[0];
  const float* Wq = (const float*)d_in[1];
  const float* Wk = (const float*)d_in[2];
  const float* Wv = (const float*)d_in[3];
  const float* Wo = (const float*)d_in[4];
  float* out = (float*)d_out;

  char* ws = (char*)d_ws;
  size_t off = 0;
  auto alloc = [&](size_t bytes) {
    void* p = ws + off;
    off += (bytes + 255) & ~(size_t)255;
    return p;
  };
  __hip_bfloat16* xb   = (__hip_bfloat16*)alloc((size_t)MR * TC * 2);
  __hip_bfloat16* wqkv = (__hip_bfloat16*)alloc((size_t)NQKV * TC * 2);
  __hip_bfloat16* wo   = (__hip_bfloat16*)alloc((size_t)TC * TC * 2);
  __hip_bfloat16* qkv  = (__hip_bfloat16*)alloc((size_t)MR * NQKV * 2);
  __hip_bfloat16* q_l  = (__hip_bfloat16*)alloc((size_t)TB * NH * TT * HD * 2);
  __hip_bfloat16* k_l  = (__hip_bfloat16*)alloc((size_t)TB * NKV * TT * HD * 2);
  __hip_bfloat16* vt_l = (__hip_bfloat16*)alloc((size_t)TB * NKV * HD * TT * 2);
  __hip_bfloat16* yb   = (__hip_bfloat16*)alloc((size_t)MR * TC * 2);

  k_cvt5<<<dim3((MR * TC / 4 + 255) / 256, 5), 256, 0, stream>>>(
      x, Wq, Wk, Wv, Wo,
      xb, wqkv, wqkv + (size_t)NQ * TC, wqkv + (size_t)(NQ + NK) * TC, wo);

  // GEMM1: 4096x3072x2048 -> 256^2 4-phase pipeline, grid 12x16 = 192 blocks
  k_gemm256<<<dim3(NQKV / 256, MR / 256), 512, 0, stream>>>(
      xb, wqkv, qkv, MR, NQKV, TC);

  k_prep<<<ROPE_BLOCKS + TB * NKV * (TT / 64), 256, 0, stream>>>(qkv, q_l, k_l, vt_l);

  // flash attention: 16 q-tiles x 16 heads x 2 batch = 512 blocks
  k_attn<<<(TT / 128) * NH * TB, 256, 0, stream>>>(q_l, k_l, vt_l, yb);

  // GEMM2: 4096x2048x2048 -> 256x128 2-phase pipeline, grid 16x16 = 256 blocks
  k_gemm2n<<<dim3(TC / 128, MR / 256), 512, 0, stream>>>(
      yb, wo, out, MR, TC, TC);
}

// Round 9
// 313.480 us; speedup vs baseline: 1.0022x; 1.0022x over previous
//
#include <hip/hip_runtime.h>
#include <hip/hip_bf16.h>
#include <cstdint>
#include <math.h>

#define DEVINL __device__ __forceinline__

typedef __attribute__((ext_vector_type(8))) __bf16 bf16x8;
typedef __attribute__((ext_vector_type(4))) float floatx4;
typedef __attribute__((ext_vector_type(4))) int intx4;

constexpr int TB = 2;        // batch
constexpr int TT = 2048;     // seq len
constexpr int TC = 2048;     // channels
constexpr int NH = 16, NKV = 4, HD = 128;
constexpr int MR = TB * TT;           // 4096 token rows
constexpr int NQ = NH * HD;           // 2048
constexpr int NK = NKV * HD;          // 512
constexpr int NQKV = NQ + 2 * NK;     // 3072

// ---------- helpers ----------
DEVINL unsigned bfbits(float f) {  // fp32 -> bf16 bits, RNE
  unsigned u = __builtin_bit_cast(unsigned, f);
  return (u + 0x7FFFu + ((u >> 16) & 1u)) >> 16;
}
DEVINL int pk2(float a, float b) {  // packed fp32x2 -> bf16x2 (v_cvt_pk_bf16_f32)
  union { __hip_bfloat162 h; int i; } u;
  u.h = __float22bfloat162_rn(float2{a, b});
  return u.i;
}
DEVINL void gl_lds16(const __hip_bfloat16* g, __hip_bfloat16* l) {
  __builtin_amdgcn_global_load_lds(
      (const __attribute__((address_space(1))) unsigned int*)g,
      (__attribute__((address_space(3))) unsigned int*)l, 16, 0, 0);
}
DEVINL floatx4 mfma16(bf16x8 a, bf16x8 b, floatx4 c) {
  return __builtin_amdgcn_mfma_f32_16x16x32_bf16(a, b, c, 0, 0, 0);
}
DEVINL void cstore(float* p, float v) { *p = v; }
DEVINL void cstore(__hip_bfloat16* p, float v) { *(unsigned short*)p = (unsigned short)bfbits(v); }

// ---------- fused fp32 -> bf16 convert (all 5 inputs, one launch) ----------
__global__ __launch_bounds__(256) void k_cvt5(
    const float* __restrict__ s0, const float* __restrict__ s1,
    const float* __restrict__ s2, const float* __restrict__ s3,
    const float* __restrict__ s4,
    __hip_bfloat16* __restrict__ d0, __hip_bfloat16* __restrict__ d1,
    __hip_bfloat16* __restrict__ d2, __hip_bfloat16* __restrict__ d3,
    __hip_bfloat16* __restrict__ d4) {
  const float* s;
  __hip_bfloat16* d;
  int n;
  switch (blockIdx.y) {
    case 0: s = s0; d = d0; n = MR * TC; break;
    case 1: s = s1; d = d1; n = NQ * TC; break;
    case 2: s = s2; d = d2; n = NK * TC; break;
    case 3: s = s3; d = d3; n = NK * TC; break;
    default: s = s4; d = d4; n = TC * TC; break;
  }
  int i = (blockIdx.x * 256 + threadIdx.x) * 4;
  if (i >= n) return;
  float4 v = *(const float4*)(s + i);
  ushort4 o;
  o.x = (unsigned short)bfbits(v.x);
  o.y = (unsigned short)bfbits(v.y);
  o.z = (unsigned short)bfbits(v.z);
  o.w = (unsigned short)bfbits(v.w);
  *(ushort4*)(d + i) = o;
}

// ---------- GEMM 128x128 (m97 structure + BK=64 + XOR swizzle) ----------
// R3's verified config -- best measured total used this for BOTH GEMMs;
// the 256^2 / 256x128 pipelined variants measured consistently ~+2 us.
template <typename OUT_T>
__global__ __launch_bounds__(256, 2) void k_gemm_bt(
    const __hip_bfloat16* __restrict__ A, const __hip_bfloat16* __restrict__ B,
    OUT_T* __restrict__ C, int M, int N, int K) {
  __shared__ __align__(16) __hip_bfloat16 As[128 * 64];  // 16 KB
  __shared__ __align__(16) __hip_bfloat16 Bs[128 * 64];  // 16 KB
  const int tid = threadIdx.x;
  const int lane = tid & 63, w = tid >> 6;
  const int q15 = lane & 15, quad = lane >> 4;
  const int wm = w >> 1, wn = w & 1;
  const int tm = blockIdx.y, tn = blockIdx.x;

  const int r0 = tid >> 3;
  const int csw = ((tid & 7) ^ (r0 & 7)) * 8;
  const __hip_bfloat16* ag = A + (size_t)(tm * 128 + r0) * K + csw;
  const __hip_bfloat16* bg = B + (size_t)(tn * 128 + r0) * K + csw;
  __hip_bfloat16* lA = As + (tid & ~63) * 8;  // wave-uniform base + lane*16B
  __hip_bfloat16* lB = Bs + (tid & ~63) * 8;

  floatx4 acc[4][4] = {};
  for (int k0 = 0; k0 < K; k0 += 64) {
    __syncthreads();
#pragma unroll
    for (int i = 0; i < 4; i++) {
      gl_lds16(ag + (size_t)(i * 32) * K + k0, lA + i * 2048);
      gl_lds16(bg + (size_t)(i * 32) * K + k0, lB + i * 2048);
    }
    __syncthreads();
#pragma unroll
    for (int kh = 0; kh < 2; kh++) {
      bf16x8 af[4], bfr[4];
#pragma unroll
      for (int i = 0; i < 4; i++)
        af[i] = *(const bf16x8*)(As + (wm * 64 + i * 16 + q15) * 64 +
                                 (((kh * 4 + quad) ^ (q15 & 7)) * 8));
#pragma unroll
      for (int i = 0; i < 4; i++)
        bfr[i] = *(const bf16x8*)(Bs + (wn * 64 + i * 16 + q15) * 64 +
                                  (((kh * 4 + quad) ^ (q15 & 7)) * 8));
#pragma unroll
      for (int mi = 0; mi < 4; mi++)
#pragma unroll
        for (int ni = 0; ni < 4; ni++)
          acc[mi][ni] = mfma16(af[mi], bfr[ni], acc[mi][ni]);
    }
  }
#pragma unroll
  for (int mi = 0; mi < 4; mi++) {
    int row0 = tm * 128 + wm * 64 + mi * 16 + quad * 4;
#pragma unroll
    for (int ni = 0; ni < 4; ni++) {
      int col = tn * 128 + wn * 64 + ni * 16 + q15;
#pragma unroll
      for (int r = 0; r < 4; r++)
        cstore(C + (size_t)(row0 + r) * N + col, acc[mi][ni][r]);
    }
  }
}

// ---------- fused (RMSNorm + RoPE + layout) and V-transpose, one launch ----------
constexpr int ROPE_BLOCKS = (MR * 20) / 4;  // 20480
__global__ __launch_bounds__(256) void k_prep(
    const __hip_bfloat16* __restrict__ qkv,
    __hip_bfloat16* __restrict__ q_l, __hip_bfloat16* __restrict__ k_l,
    __hip_bfloat16* __restrict__ vt) {
  if (blockIdx.x < ROPE_BLOCKS) {
    int gw = (blockIdx.x * 256 + threadIdx.x) >> 6;
    int lane = threadIdx.x & 63;
    int head = gw % 20;
    int bt = gw / 20;
    int b = bt >> 11, t = bt & (TT - 1);
    bool isq = head < NH;
    int h = isq ? head : head - NH;
    const __hip_bfloat16* src = qkv + (size_t)bt * NQKV + (isq ? h * HD : NQ + h * HD);
    float x1 = __bfloat162float(src[lane]);
    float x2 = __bfloat162float(src[lane + 64]);
    float ss = x1 * x1 + x2 * x2;
#pragma unroll
    for (int m = 1; m < 64; m <<= 1) ss += __shfl_xor(ss, m, 64);
    float rinv = rsqrtf(ss * (1.0f / 128.0f) + 1.1920928955078125e-07f);
    float ang = (float)t * exp2f((float)lane * -(13.287712379549449f / 64.0f));
    float sv = sinf(ang), cv = cosf(ang);
    float scale = isq ? (1.4426950408889634f * 0.08838834764831845f) : 1.0f;
    float o1 = (x1 * cv + x2 * sv) * rinv * scale;
    float o2 = (x2 * cv - x1 * sv) * rinv * scale;
    __hip_bfloat16* dst = isq ? q_l + ((size_t)(b * NH + h) * TT + t) * HD
                              : k_l + ((size_t)(b * NKV + h) * TT + t) * HD;
    *(unsigned short*)(dst + lane) = (unsigned short)bfbits(o1);
    *(unsigned short*)(dst + lane + 64) = (unsigned short)bfbits(o2);
  } else {
    __shared__ __hip_bfloat16 tile[64][130];
    int bid = blockIdx.x - ROPE_BLOCKS;
    int t0 = (bid & 31) * 64;
    int hk = (bid >> 5) & 3;
    int b = bid >> 7;
    int tid = threadIdx.x;
#pragma unroll
    for (int j = 0; j < 32; j++) {
      int e = j * 256 + tid;
      int tt = e >> 7, d = e & 127;
      tile[tt][d] = qkv[(size_t)(b * TT + t0 + tt) * NQKV + NQ + NK + hk * HD + d];
    }
    __syncthreads();
#pragma unroll
    for (int j = 0; j < 32; j++) {
      int e = j * 256 + tid;
      int d = e >> 6, tt = e & 63;
      vt[(((size_t)(b * NKV + hk)) * HD + d) * TT + t0 + tt] = tile[tt][d];
    }
  }
}

// ---------- flash attention v9 (causal, GQA) ----------
// Occupancy rebuild: R8 proved the 128-q/2-block-per-CU structure is
// wave-starved (conflicts->0 changed nothing; all pipes <=35%; 2 waves/SIMD).
// v9: QBLK=64 (4 waves x 16 q), KVBLK=32, LDS 32 KB -> grid 1024 blocks =
// 4 blocks/CU x 4 waves = 4 waves/SIMD (2x residency, 4 independent barrier
// domains/CU). Every formula is a restriction of v8's verified ones (kt 4->2,
// qh 2->1, kc 2->1; same swizzles, same permlane P transport). Work-balanced
// qt map: each CU's 4 co-resident slots {sl, sl+8, sl+16, sl+24} get qt
// {31-sl, sl-8, 39-sl, sl-16} -> constant sum 62.
__global__ __launch_bounds__(256, 4) void k_attn(
    const __hip_bfloat16* __restrict__ q_l, const __hip_bfloat16* __restrict__ k_l,
    const __hip_bfloat16* __restrict__ vt_l, __hip_bfloat16* __restrict__ y) {
  __shared__ __align__(16) __hip_bfloat16 Ks[2][32 * 128];   // 16 KB
  __shared__ __align__(16) __hip_bfloat16 Vs[2][128 * 32];   // 16 KB
  const int tid = threadIdx.x, lane = tid & 63, w = tid >> 6;
  const int q15 = lane & 15, quad = lane >> 4;
  const int id = blockIdx.x;
  const int sl = id >> 5;  // 32 slots of 32 blocks
  const int qt = (sl < 8) ? (31 - sl)
               : (sl < 16) ? (sl - 8)
               : (sl < 24) ? (39 - sl)
                           : (sl - 16);
  const int h = id & 15, b = (id >> 4) & 1;
  const int hk = h >> 2;
  const int nkb = 2 * qt + 2;  // k-blocks of 32 up to (qt+1)*64

  const __hip_bfloat16* kbase = k_l + (size_t)(b * NKV + hk) * TT * HD;
  const __hip_bfloat16* vbase = vt_l + (size_t)(b * NKV + hk) * HD * TT;
  const __hip_bfloat16* qbase = q_l + ((size_t)(b * NH + h) * TT + qt * 64) * HD;

  auto stage = [&](int kb, int buf) {
#pragma unroll
    for (int i = 0; i < 2; i++) {
      int s = i * 256 + tid;
      int rk = s >> 4, ck = s & 15;
      gl_lds16(kbase + (size_t)(kb * 32 + rk) * HD + (ck ^ (rk & 15)) * 8,
               Ks[buf] + (i * 256 + (tid & ~63)) * 8);
      int rv = s >> 2, cv = s & 3;
      gl_lds16(vbase + (size_t)rv * TT + kb * 32 + (cv ^ (rv & 3)) * 8,
               Vs[buf] + (i * 256 + (tid & ~63)) * 8);
    }
  };

  // Q frags: wave covers q rows qt*64 + w*16 + q15
  bf16x8 qf[4];
#pragma unroll
  for (int dc = 0; dc < 4; dc++)
    qf[dc] = *(const bf16x8*)(qbase + (size_t)(w * 16 + q15) * HD + dc * 32 + quad * 8);

  floatx4 ot[8] = {};
  float lsum = 0.0f;
  int cur = 0;
  const int qg = qt * 64 + w * 16 + q15;    // this lane's q row
  const int qminw = qt * 64 + w * 16;       // wave's smallest q
  const int kb_last_w = 2 * qt + (w >> 1);  // waves 0,1 skip final all-masked iter

  for (int kb = 0; kb < nkb; kb++) {
    __syncthreads();
    if (kb == 0) {
      stage(0, cur);
      __syncthreads();
    }
    if (kb + 1 < nkb) stage(kb + 1, cur ^ 1);

    if (kb <= kb_last_w) {
      // S^T = K @ Q^T : [32 k][16 q] as two 16x16 C-tiles
      floatx4 st[2] = {};
#pragma unroll
      for (int kt = 0; kt < 2; kt++) {
        int r = kt * 16 + q15;
#pragma unroll
        for (int dc = 0; dc < 4; dc++) {
          int c = dc * 4 + quad;
          bf16x8 kf = *(const bf16x8*)(Ks[cur] + (r * 16 + (c ^ (r & 15))) * 8);
          st[kt] = mfma16(kf, qf[dc], st[kt]);
        }
      }
      if (kb * 32 + 31 > qminw) {  // causal mask (diagonal region for this wave)
#pragma unroll
        for (int kt = 0; kt < 2; kt++)
#pragma unroll
          for (int r = 0; r < 4; r++)
            if (kb * 32 + kt * 16 + quad * 4 + r > qg) st[kt][r] = -INFINITY;
      }
      // static-max softmax: p = exp2(s); pack P per-kt (C layout dwords)
      int pA[2], pB[2];
#pragma unroll
      for (int kt = 0; kt < 2; kt++) {
        float p0 = exp2f(st[kt][0]);
        float p1 = exp2f(st[kt][1]);
        float p2 = exp2f(st[kt][2]);
        float p3 = exp2f(st[kt][3]);
        lsum += (p0 + p1) + (p2 + p3);
        pA[kt] = pk2(p0, p1);
        pB[kt] = pk2(p2, p3);
      }
      // P B-frag via permlane transport (v8-verified lane algebra, kc=0 only)
      bf16x8 pf;
      {
        int u0 = pA[0], u1 = pA[1], v0 = pB[0], v1 = pB[1];
        asm("v_permlane32_swap_b32 %0, %1" : "+v"(u0), "+v"(u1));
        asm("v_permlane16_swap_b32 %0, %1" : "+v"(u0), "+v"(u1));
        asm("v_permlane32_swap_b32 %0, %1" : "+v"(v0), "+v"(v1));
        asm("v_permlane16_swap_b32 %0, %1" : "+v"(v0), "+v"(v1));
        intx4 wi;
        wi[0] = u0; wi[1] = v0; wi[2] = u1; wi[3] = v1;
        pf = __builtin_bit_cast(bf16x8, wi);
      }
      // PV: y^T[128 d][16 q] += V^T @ P^T (k=32 -> one MFMA per d-tile)
#pragma unroll
      for (int dt = 0; dt < 8; dt++) {
        int r = dt * 16 + q15;
        bf16x8 vf = *(const bf16x8*)(Vs[cur] + (r * 4 + (quad ^ (r & 3))) * 8);
        ot[dt] = mfma16(vf, pf, ot[dt]);
      }
    }
    cur ^= 1;
  }
  // epilogue: reduce l across quads, normalize, store y[b][t][h*128+d]
  float ls = lsum;
  ls += __shfl_xor(ls, 16, 64);
  ls += __shfl_xor(ls, 32, 64);
  float linv = 1.0f / ls;
  const int t = qt * 64 + w * 16 + q15;
  __hip_bfloat16* yrow = y + (size_t)(b * TT + t) * TC + h * HD;
#pragma unroll
  for (int dt = 0; dt < 8; dt++) {
    int d = dt * 16 + quad * 4;
    ushort4 o;
    o.x = (unsigned short)bfbits(ot[dt][0] * linv);
    o.y = (unsigned short)bfbits(ot[dt][1] * linv);
    o.z = (unsigned short)bfbits(ot[dt][2] * linv);
    o.w = (unsigned short)bfbits(ot[dt][3] * linv);
    *(ushort4*)(yrow + d) = o;
  }
}

// ---------- launcher ----------
extern "C" void kernel_launch(void* const* d_in, const int* in_sizes, int n_in,
                              void* d_out, int out_size, void* d_ws, size_t ws_size,
                              hipStream_t stream) {
  (void)in_sizes; (void)n_in; (void)out_size; (void)ws_size;
  const float* x  = (const float*)d_in[0];
  const float* Wq = (const float*)d_in[1];
  const float* Wk = (const float*)d_in[2];
  const float* Wv = (const float*)d_in[3];
  const float* Wo = (const float*)d_in[4];
  float* out = (float*)d_out;

  char* ws = (char*)d_ws;
  size_t off = 0;
  auto alloc = [&](size_t bytes) {
    void* p = ws + off;
    off += (bytes + 255) & ~(size_t)255;
    return p;
  };
  __hip_bfloat16* xb   = (__hip_bfloat16*)alloc((size_t)MR * TC * 2);
  __hip_bfloat16* wqkv = (__hip_bfloat16*)alloc((size_t)NQKV * TC * 2);
  __hip_bfloat16* wo   = (__hip_bfloat16*)alloc((size_t)TC * TC * 2);
  __hip_bfloat16* qkv  = (__hip_bfloat16*)alloc((size_t)MR * NQKV * 2);
  __hip_bfloat16* q_l  = (__hip_bfloat16*)alloc((size_t)TB * NH * TT * HD * 2);
  __hip_bfloat16* k_l  = (__hip_bfloat16*)alloc((size_t)TB * NKV * TT * HD * 2);
  __hip_bfloat16* vt_l = (__hip_bfloat16*)alloc((size_t)TB * NKV * HD * TT * 2);
  __hip_bfloat16* yb   = (__hip_bfloat16*)alloc((size_t)MR * TC * 2);

  k_cvt5<<<dim3((MR * TC / 4 + 255) / 256, 5), 256, 0, stream>>>(
      x, Wq, Wk, Wv, Wo,
      xb, wqkv, wqkv + (size_t)NQ * TC, wqkv + (size_t)(NQ + NK) * TC, wo);

  // GEMM1: 4096x3072x2048, 128^2 BK=64+swizzle, grid 24x32 = 768 blocks
  k_gemm_bt<__hip_bfloat16><<<dim3(NQKV / 128, MR / 128), 256, 0, stream>>>(
      xb, wqkv, qkv, MR, NQKV, TC);

  k_prep<<<ROPE_BLOCKS + TB * NKV * (TT / 64), 256, 0, stream>>>(qkv, q_l, k_l, vt_l);

  // flash attention: 32 q-tiles x 16 heads x 2 batch = 1024 blocks (4/CU)
  k_attn<<<(TT / 64) * NH * TB, 256, 0, stream>>>(q_l, k_l, vt_l, yb);

  // GEMM2: 4096x2048x2048, 128^2 BK=64+swizzle, grid 16x32 = 512 blocks
  k_gemm_bt<float><<<dim3(TC / 128, MR / 128), 256, 0, stream>>>(
      yb, wo, out, MR, TC, TC);
}

// Round 10
// 290.606 us; speedup vs baseline: 1.0811x; 1.0787x over previous
//
#include <hip/hip_runtime.h>
#include <hip/hip_bf16.h>
#include <cstdint>
#include <math.h>

#define DEVINL __device__ __forceinline__

typedef __attribute__((ext_vector_type(8))) __bf16 bf16x8;
typedef __attribute__((ext_vector_type(4))) float floatx4;
typedef __attribute__((ext_vector_type(4))) int intx4;

constexpr int TB = 2;        // batch
constexpr int TT = 2048;     // seq len
constexpr int TC = 2048;     // channels
constexpr int NH = 16, NKV = 4, HD = 128;
constexpr int MR = TB * TT;           // 4096 token rows
constexpr int NQ = NH * HD;           // 2048
constexpr int NK = NKV * HD;          // 512
constexpr int NQKV = NQ + 2 * NK;     // 3072

// ---------- helpers ----------
DEVINL unsigned bfbits(float f) {  // fp32 -> bf16 bits, RNE
  unsigned u = __builtin_bit_cast(unsigned, f);
  return (u + 0x7FFFu + ((u >> 16) & 1u)) >> 16;
}
DEVINL int pk2(float a, float b) {  // packed fp32x2 -> bf16x2 (v_cvt_pk_bf16_f32)
  union { __hip_bfloat162 h; int i; } u;
  u.h = __float22bfloat162_rn(float2{a, b});
  return u.i;
}
DEVINL void gl_lds16(const __hip_bfloat16* g, __hip_bfloat16* l) {
  __builtin_amdgcn_global_load_lds(
      (const __attribute__((address_space(1))) unsigned int*)g,
      (__attribute__((address_space(3))) unsigned int*)l, 16, 0, 0);
}
DEVINL floatx4 mfma16(bf16x8 a, bf16x8 b, floatx4 c) {
  return __builtin_amdgcn_mfma_f32_16x16x32_bf16(a, b, c, 0, 0, 0);
}
DEVINL void cstore(float* p, float v) { *p = v; }
DEVINL void cstore(__hip_bfloat16* p, float v) { *(unsigned short*)p = (unsigned short)bfbits(v); }

// ---------- fused fp32 -> bf16 convert (x, Wq, Wk, Wv, Wo -> bf16) ----------
__global__ __launch_bounds__(256) void k_cvt5(
    const float* __restrict__ s0, const float* __restrict__ s1,
    const float* __restrict__ s2, const float* __restrict__ s3,
    const float* __restrict__ s4,
    __hip_bfloat16* __restrict__ d0, __hip_bfloat16* __restrict__ d1,
    __hip_bfloat16* __restrict__ d2, __hip_bfloat16* __restrict__ d3,
    __hip_bfloat16* __restrict__ d4) {
  const float* s;
  __hip_bfloat16* d;
  int n;
  switch (blockIdx.y) {
    case 0: s = s0; d = d0; n = MR * TC; break;
    case 1: s = s1; d = d1; n = NQ * TC; break;
    case 2: s = s2; d = d2; n = NK * TC; break;
    case 3: s = s3; d = d3; n = NK * TC; break;
    default: s = s4; d = d4; n = TC * TC; break;
  }
  int i = (blockIdx.x * 256 + threadIdx.x) * 4;
  if (i >= n) return;
  float4 v = *(const float4*)(s + i);
  ushort4 o;
  o.x = (unsigned short)bfbits(v.x);
  o.y = (unsigned short)bfbits(v.y);
  o.z = (unsigned short)bfbits(v.z);
  o.w = (unsigned short)bfbits(v.w);
  *(ushort4*)(d + i) = o;
}

// ---------- GEMM 128x128 (m97 + BK=64 + XOR swizzle) for GEMM2 ----------
template <typename OUT_T>
__global__ __launch_bounds__(256, 2) void k_gemm_bt(
    const __hip_bfloat16* __restrict__ A, const __hip_bfloat16* __restrict__ B,
    OUT_T* __restrict__ C, int M, int N, int K) {
  __shared__ __align__(16) __hip_bfloat16 As[128 * 64];  // 16 KB
  __shared__ __align__(16) __hip_bfloat16 Bs[128 * 64];  // 16 KB
  const int tid = threadIdx.x;
  const int lane = tid & 63, w = tid >> 6;
  const int q15 = lane & 15, quad = lane >> 4;
  const int wm = w >> 1, wn = w & 1;
  const int tm = blockIdx.y, tn = blockIdx.x;

  const int r0 = tid >> 3;
  const int csw = ((tid & 7) ^ (r0 & 7)) * 8;
  const __hip_bfloat16* ag = A + (size_t)(tm * 128 + r0) * K + csw;
  const __hip_bfloat16* bg = B + (size_t)(tn * 128 + r0) * K + csw;
  __hip_bfloat16* lA = As + (tid & ~63) * 8;  // wave-uniform base + lane*16B
  __hip_bfloat16* lB = Bs + (tid & ~63) * 8;

  floatx4 acc[4][4] = {};
  for (int k0 = 0; k0 < K; k0 += 64) {
    __syncthreads();
#pragma unroll
    for (int i = 0; i < 4; i++) {
      gl_lds16(ag + (size_t)(i * 32) * K + k0, lA + i * 2048);
      gl_lds16(bg + (size_t)(i * 32) * K + k0, lB + i * 2048);
    }
    __syncthreads();
#pragma unroll
    for (int kh = 0; kh < 2; kh++) {
      bf16x8 af[4], bfr[4];
#pragma unroll
      for (int i = 0; i < 4; i++)
        af[i] = *(const bf16x8*)(As + (wm * 64 + i * 16 + q15) * 64 +
                                 (((kh * 4 + quad) ^ (q15 & 7)) * 8));
#pragma unroll
      for (int i = 0; i < 4; i++)
        bfr[i] = *(const bf16x8*)(Bs + (wn * 64 + i * 16 + q15) * 64 +
                                  (((kh * 4 + quad) ^ (q15 & 7)) * 8));
#pragma unroll
      for (int mi = 0; mi < 4; mi++)
#pragma unroll
        for (int ni = 0; ni < 4; ni++)
          acc[mi][ni] = mfma16(af[mi], bfr[ni], acc[mi][ni]);
    }
  }
#pragma unroll
  for (int mi = 0; mi < 4; mi++) {
    int row0 = tm * 128 + wm * 64 + mi * 16 + quad * 4;
#pragma unroll
    for (int ni = 0; ni < 4; ni++) {
      int col = tn * 128 + wn * 64 + ni * 16 + q15;
#pragma unroll
      for (int r = 0; r < 4; r++)
        cstore(C + (size_t)(row0 + r) * N + col, acc[mi][ni][r]);
    }
  }
}

// ---------- GEMM1 fused: qkv-proj + RMSNorm + RoPE + V-transpose ----------
// Same 128^2 BK=64+swizzle K-loop as k_gemm_bt, but the C-tile is never
// written to global: tile-N = 128 = HD, so each C-tile is exactly one head x
// 128 tokens -- the full RMSNorm axis is block-local. Epilogue: round acc to
// bf16 into a padded LDS tile [128][130] (aliased over As/Bs, 33.3 KB),
// barrier, then (a) Q/K tiles: each wave norms+RoPEs 32 rows (identical code
// to the old k_prep, reading LDS) and writes q_l/k_l; (b) V tiles: padded
// LDS transpose, coalesced 2B writes to vt. Numerics are BIT-IDENTICAL to
// the old GEMM->qkv->k_prep path (LDS holds the same bf16 values qkv held).
// Eliminates the qkv round-trip (~63 MB) and the entire k_prep launch.
__global__ __launch_bounds__(256, 2) void k_gemm_qkv(
    const __hip_bfloat16* __restrict__ A, const __hip_bfloat16* __restrict__ B,
    __hip_bfloat16* __restrict__ q_l, __hip_bfloat16* __restrict__ k_l,
    __hip_bfloat16* __restrict__ vt) {
  constexpr int K = TC;
  // union: K-loop uses [0,16384) as As/Bs; epilogue uses [0,16640) as tile
  __shared__ __align__(16) __hip_bfloat16 smem[128 * 130];  // 33.3 KB
  __hip_bfloat16* As = smem;
  __hip_bfloat16* Bs = smem + 128 * 64;
  const int tid = threadIdx.x;
  const int lane = tid & 63, w = tid >> 6;
  const int q15 = lane & 15, quad = lane >> 4;
  const int wm = w >> 1, wn = w & 1;
  const int tm = blockIdx.y, tn = blockIdx.x;

  const int r0 = tid >> 3;
  const int csw = ((tid & 7) ^ (r0 & 7)) * 8;
  const __hip_bfloat16* ag = A + (size_t)(tm * 128 + r0) * K + csw;
  const __hip_bfloat16* bg = B + (size_t)(tn * 128 + r0) * K + csw;
  __hip_bfloat16* lA = As + (tid & ~63) * 8;
  __hip_bfloat16* lB = Bs + (tid & ~63) * 8;

  floatx4 acc[4][4] = {};
  for (int k0 = 0; k0 < K; k0 += 64) {
    __syncthreads();
#pragma unroll
    for (int i = 0; i < 4; i++) {
      gl_lds16(ag + (size_t)(i * 32) * K + k0, lA + i * 2048);
      gl_lds16(bg + (size_t)(i * 32) * K + k0, lB + i * 2048);
    }
    __syncthreads();
#pragma unroll
    for (int kh = 0; kh < 2; kh++) {
      bf16x8 af[4], bfr[4];
#pragma unroll
      for (int i = 0; i < 4; i++)
        af[i] = *(const bf16x8*)(As + (wm * 64 + i * 16 + q15) * 64 +
                                 (((kh * 4 + quad) ^ (q15 & 7)) * 8));
#pragma unroll
      for (int i = 0; i < 4; i++)
        bfr[i] = *(const bf16x8*)(Bs + (wn * 64 + i * 16 + q15) * 64 +
                                  (((kh * 4 + quad) ^ (q15 & 7)) * 8));
#pragma unroll
      for (int mi = 0; mi < 4; mi++)
#pragma unroll
        for (int ni = 0; ni < 4; ni++)
          acc[mi][ni] = mfma16(af[mi], bfr[ni], acc[mi][ni]);
    }
  }

  // ---- epilogue: acc -> bf16 -> padded LDS tile [128 t][130] ----
  __syncthreads();  // all waves done reading As/Bs
#pragma unroll
  for (int mi = 0; mi < 4; mi++)
#pragma unroll
    for (int ni = 0; ni < 4; ni++) {
      int row = wm * 64 + mi * 16 + quad * 4;
      int col = wn * 64 + ni * 16 + q15;
#pragma unroll
      for (int r = 0; r < 4; r++)
        *(unsigned short*)(smem + (row + r) * 130 + col) =
            (unsigned short)bfbits(acc[mi][ni][r]);
    }
  __syncthreads();

  const int b = tm >> 4;  // batch of this 128-token row block
  if (tn < NH + NKV) {
    // Q head (tn<16) or K head: RMSNorm + RoPE, wave w covers rows w*32..+32
    const bool isq = tn < NH;
    const int h = isq ? tn : tn - NH;
    const float scale = isq ? (1.4426950408889634f * 0.08838834764831845f) : 1.0f;
    __hip_bfloat16* base = isq ? q_l + (size_t)(b * NH + h) * TT * HD
                               : k_l + (size_t)(b * NKV + h) * TT * HD;
    const float ifreq = exp2f((float)lane * -(13.287712379549449f / 64.0f));
    for (int j = 0; j < 32; ++j) {
      int row = w * 32 + j;
      int t = (tm & 15) * 128 + row;  // token index within batch
      float x1 = __bfloat162float(smem[row * 130 + lane]);
      float x2 = __bfloat162float(smem[row * 130 + 64 + lane]);
      float ss = x1 * x1 + x2 * x2;
#pragma unroll
      for (int m = 1; m < 64; m <<= 1) ss += __shfl_xor(ss, m, 64);
      float rinv = rsqrtf(ss * (1.0f / 128.0f) + 1.1920928955078125e-07f);
      float ang = (float)t * ifreq;
      float sv = sinf(ang), cv = cosf(ang);
      float o1 = (x1 * cv + x2 * sv) * rinv * scale;
      float o2 = (x2 * cv - x1 * sv) * rinv * scale;
      __hip_bfloat16* dst = base + (size_t)t * HD;
      *(unsigned short*)(dst + lane) = (unsigned short)bfbits(o1);
      *(unsigned short*)(dst + lane + 64) = (unsigned short)bfbits(o2);
    }
  } else {
    // V head: transpose tile [128 t][128 d] -> vt[d][t], coalesced 2B stores
    const int hv = tn - NH - NKV;
    __hip_bfloat16* vbase = vt + (size_t)(b * NKV + hv) * HD * TT + (tm & 15) * 128;
    for (int j = 0; j < 64; ++j) {
      int e = j * 256 + tid;
      int d = e >> 7, tt = e & 127;
      vbase[(size_t)d * TT + tt] = smem[tt * 130 + d];
    }
  }
}

// ---------- flash attention v8 (causal, GQA) ----------
// Verified local optimum (78 us, R8): 128-q tile, 4 waves, K/V dbuf gl_lds
// staging with XOR swizzle, in-register P transport via permlane swaps
// (bank conflicts = 0). R9 proved occupancy is NOT the limiter (2x waves ->
// slower); the 78 us floor is the per-iteration serial chain.
__global__ __launch_bounds__(256, 2) void k_attn(
    const __hip_bfloat16* __restrict__ q_l, const __hip_bfloat16* __restrict__ k_l,
    const __hip_bfloat16* __restrict__ vt_l, __hip_bfloat16* __restrict__ y) {
  __shared__ __align__(16) __hip_bfloat16 Ks[2][64 * 128];   // 32 KB
  __shared__ __align__(16) __hip_bfloat16 Vs[2][128 * 64];   // 32 KB
  const int tid = threadIdx.x, lane = tid & 63, w = tid >> 6;
  const int q15 = lane & 15, quad = lane >> 4;
  const int id = blockIdx.x;
  const int sl = id >> 5;  // 16 slots of 32 blocks
  const int qt = (sl < 8) ? (15 - sl) : (sl - 8);  // pair-balanced mapping
  const int h = id & 15, b = (id >> 4) & 1;
  const int hk = h >> 2;
  const int nkb = 2 * qt + 2;

  const __hip_bfloat16* kbase = k_l + (size_t)(b * NKV + hk) * TT * HD;
  const __hip_bfloat16* vbase = vt_l + (size_t)(b * NKV + hk) * HD * TT;
  const __hip_bfloat16* qbase = q_l + ((size_t)(b * NH + h) * TT + qt * 128) * HD;

  auto stage = [&](int kb, int buf) {
#pragma unroll
    for (int i = 0; i < 4; i++) {
      int s = i * 256 + tid;
      int rk = s >> 4, ck = s & 15;
      gl_lds16(kbase + (size_t)(kb * 64 + rk) * HD + (ck ^ (rk & 15)) * 8,
               Ks[buf] + (i * 256 + (tid & ~63)) * 8);
      int rv = s >> 3, cv = s & 7;
      gl_lds16(vbase + (size_t)rv * TT + kb * 64 + (cv ^ (rv & 7)) * 8,
               Vs[buf] + (i * 256 + (tid & ~63)) * 8);
    }
  };

  // Q frags: wave covers q rows qt*128 + w*32 + qh*16 + q15
  bf16x8 qf[4][2];
#pragma unroll
  for (int dc = 0; dc < 4; dc++)
#pragma unroll
    for (int qh = 0; qh < 2; qh++)
      qf[dc][qh] = *(const bf16x8*)(qbase + (size_t)(w * 32 + qh * 16 + q15) * HD +
                                    dc * 32 + quad * 8);

  floatx4 ot[8][2] = {};
  float lsum[2] = {0.0f, 0.0f};
  int cur = 0;
  const int kb_last_w = 2 * qt + (w >> 1);  // waves 0,1 skip final all-masked iter

  for (int kb = 0; kb < nkb; kb++) {
    __syncthreads();
    if (kb == 0) {
      stage(0, cur);
      __syncthreads();
    }
    if (kb + 1 < nkb) stage(kb + 1, cur ^ 1);

    if (kb <= kb_last_w) {
      // S^T = K @ Q^T : [64 k][32 q] as two 16-col C-tiles per kt
      floatx4 st[4][2] = {};
#pragma unroll
      for (int kt = 0; kt < 4; kt++) {
        int r = kt * 16 + q15;
#pragma unroll
        for (int dc = 0; dc < 4; dc++) {
          int c = dc * 4 + quad;
          bf16x8 kf = *(const bf16x8*)(Ks[cur] + (r * 16 + (c ^ (r & 15))) * 8);
          st[kt][0] = mfma16(kf, qf[dc][0], st[kt][0]);
          st[kt][1] = mfma16(kf, qf[dc][1], st[kt][1]);
        }
      }
      if (kb >= 2 * qt) {  // causal mask (diagonal region)
#pragma unroll
        for (int qh = 0; qh < 2; qh++) {
          int qg = qt * 128 + w * 32 + qh * 16 + q15;
#pragma unroll
          for (int kt = 0; kt < 4; kt++)
#pragma unroll
            for (int r = 0; r < 4; r++)
              if (kb * 64 + kt * 16 + quad * 4 + r > qg) st[kt][qh][r] = -INFINITY;
        }
      }
      // static-max softmax: p = exp2(s); pack P into per-kt dwords (C layout)
      int pA[2][4], pB[2][4];
#pragma unroll
      for (int kt = 0; kt < 4; kt++) {
#pragma unroll
        for (int qh = 0; qh < 2; qh++) {
          float p0 = exp2f(st[kt][qh][0]);
          float p1 = exp2f(st[kt][qh][1]);
          float p2 = exp2f(st[kt][qh][2]);
          float p3 = exp2f(st[kt][qh][3]);
          lsum[qh] += (p0 + p1) + (p2 + p3);
          pA[qh][kt] = pk2(p0, p1);
          pB[qh][kt] = pk2(p2, p3);
        }
      }
      // PV: y^T[128 d][32 q] += V^T @ P^T ; P B-frags via permlane swaps
#pragma unroll
      for (int kc = 0; kc < 2; kc++) {
        bf16x8 pf[2];
#pragma unroll
        for (int qh = 0; qh < 2; qh++) {
          int u0 = pA[qh][2 * kc], u1 = pA[qh][2 * kc + 1];
          int v0 = pB[qh][2 * kc], v1 = pB[qh][2 * kc + 1];
          asm("v_permlane32_swap_b32 %0, %1" : "+v"(u0), "+v"(u1));
          asm("v_permlane16_swap_b32 %0, %1" : "+v"(u0), "+v"(u1));
          asm("v_permlane32_swap_b32 %0, %1" : "+v"(v0), "+v"(v1));
          asm("v_permlane16_swap_b32 %0, %1" : "+v"(v0), "+v"(v1));
          intx4 wi;
          wi[0] = u0; wi[1] = v0; wi[2] = u1; wi[3] = v1;
          pf[qh] = __builtin_bit_cast(bf16x8, wi);
        }
#pragma unroll
        for (int dt = 0; dt < 8; dt++) {
          int r = dt * 16 + q15, c = kc * 4 + quad;
          bf16x8 vf = *(const bf16x8*)(Vs[cur] + (r * 8 + (c ^ (r & 7))) * 8);
          ot[dt][0] = mfma16(vf, pf[0], ot[dt][0]);
          ot[dt][1] = mfma16(vf, pf[1], ot[dt][1]);
        }
      }
    }
    cur ^= 1;
  }
  // epilogue: reduce l across quads, normalize, store y[b][t][h*128+d]
#pragma unroll
  for (int qh = 0; qh < 2; qh++) {
    float ls = lsum[qh];
    ls += __shfl_xor(ls, 16, 64);
    ls += __shfl_xor(ls, 32, 64);
    float linv = 1.0f / ls;
    int t = qt * 128 + w * 32 + qh * 16 + q15;
    __hip_bfloat16* yrow = y + (size_t)(b * TT + t) * TC + h * HD;
#pragma unroll
    for (int dt = 0; dt < 8; dt++) {
      int d = dt * 16 + quad * 4;
      ushort4 o;
      o.x = (unsigned short)bfbits(ot[dt][qh][0] * linv);
      o.y = (unsigned short)bfbits(ot[dt][qh][1] * linv);
      o.z = (unsigned short)bfbits(ot[dt][qh][2] * linv);
      o.w = (unsigned short)bfbits(ot[dt][qh][3] * linv);
      *(ushort4*)(yrow + d) = o;
    }
  }
}

// ---------- launcher ----------
extern "C" void kernel_launch(void* const* d_in, const int* in_sizes, int n_in,
                              void* d_out, int out_size, void* d_ws, size_t ws_size,
                              hipStream_t stream) {
  (void)in_sizes; (void)n_in; (void)out_size; (void)ws_size;
  const float* x  = (const float*)d_in[0];
  const float* Wq = (const float*)d_in[1];
  const float* Wk = (const float*)d_in[2];
  const float* Wv = (const float*)d_in[3];
  const float* Wo = (const float*)d_in[4];
  float* out = (float*)d_out;

  char* ws = (char*)d_ws;
  size_t off = 0;
  auto alloc = [&](size_t bytes) {
    void* p = ws + off;
    off += (bytes + 255) & ~(size_t)255;
    return p;
  };
  __hip_bfloat16* xb   = (__hip_bfloat16*)alloc((size_t)MR * TC * 2);
  __hip_bfloat16* wqkv = (__hip_bfloat16*)alloc((size_t)NQKV * TC * 2);
  __hip_bfloat16* wo   = (__hip_bfloat16*)alloc((size_t)TC * TC * 2);
  __hip_bfloat16* q_l  = (__hip_bfloat16*)alloc((size_t)TB * NH * TT * HD * 2);
  __hip_bfloat16* k_l  = (__hip_bfloat16*)alloc((size_t)TB * NKV * TT * HD * 2);
  __hip_bfloat16* vt_l = (__hip_bfloat16*)alloc((size_t)TB * NKV * HD * TT * 2);
  __hip_bfloat16* yb   = (__hip_bfloat16*)alloc((size_t)MR * TC * 2);

  k_cvt5<<<dim3((MR * TC / 4 + 255) / 256, 5), 256, 0, stream>>>(
      x, Wq, Wk, Wv, Wo,
      xb, wqkv, wqkv + (size_t)NQ * TC, wqkv + (size_t)(NQ + NK) * TC, wo);

  // GEMM1 fused with RMSNorm+RoPE+V-transpose: grid 24x32, replaces k_prep
  k_gemm_qkv<<<dim3(NQKV / 128, MR / 128), 256, 0, stream>>>(
      xb, wqkv, q_l, k_l, vt_l);

  // flash attention: 16 q-tiles x 16 heads x 2 batch = 512 blocks
  k_attn<<<(TT / 128) * NH * TB, 256, 0, stream>>>(q_l, k_l, vt_l, yb);

  // GEMM2: 4096x2048x2048, 128^2 BK=64+swizzle, grid 16x32 = 512 blocks
  k_gemm_bt<float><<<dim3(TC / 128, MR / 128), 256, 0, stream>>>(
      yb, wo, out, MR, TC, TC);
}

// Round 11
// 282.602 us; speedup vs baseline: 1.1117x; 1.0283x over previous
//
#include <hip/hip_runtime.h>
#include <hip/hip_bf16.h>
#include <cstdint>
#include <math.h>

#define DEVINL __device__ __forceinline__

typedef __attribute__((ext_vector_type(8))) __bf16 bf16x8;
typedef __attribute__((ext_vector_type(4))) float floatx4;
typedef __attribute__((ext_vector_type(4))) int intx4;

constexpr int TB = 2;        // batch
constexpr int TT = 2048;     // seq len
constexpr int TC = 2048;     // channels
constexpr int NH = 16, NKV = 4, HD = 128;
constexpr int MR = TB * TT;           // 4096 token rows
constexpr int NQ = NH * HD;           // 2048
constexpr int NK = NKV * HD;          // 512
constexpr int NQKV = NQ + 2 * NK;     // 3072

// ---------- helpers ----------
DEVINL unsigned bfbits(float f) {  // fp32 -> bf16 bits, RNE
  unsigned u = __builtin_bit_cast(unsigned, f);
  return (u + 0x7FFFu + ((u >> 16) & 1u)) >> 16;
}
DEVINL int pk2(float a, float b) {  // packed fp32x2 -> bf16x2 (v_cvt_pk_bf16_f32)
  union { __hip_bfloat162 h; int i; } u;
  u.h = __float22bfloat162_rn(float2{a, b});
  return u.i;
}
DEVINL void gl_lds16(const __hip_bfloat16* g, __hip_bfloat16* l) {
  __builtin_amdgcn_global_load_lds(
      (const __attribute__((address_space(1))) unsigned int*)g,
      (__attribute__((address_space(3))) unsigned int*)l, 16, 0, 0);
}
DEVINL floatx4 mfma16(bf16x8 a, bf16x8 b, floatx4 c) {
  return __builtin_amdgcn_mfma_f32_16x16x32_bf16(a, b, c, 0, 0, 0);
}
DEVINL void cstore(float* p, float v) { *p = v; }
DEVINL void cstore(__hip_bfloat16* p, float v) { *(unsigned short*)p = (unsigned short)bfbits(v); }

// ---------- fused fp32 -> bf16 convert, exact 1-D grid ----------
// Segment prefix sums (vec4 units); every array size divides exactly.
constexpr int C0 = MR * TC / 4;        // 2097152  x
constexpr int C1 = C0 + NQ * TC / 4;   // 3145728  +Wq
constexpr int C2 = C1 + NK * TC / 4;   // 3407872  +Wk
constexpr int C3 = C2 + NK * TC / 4;   // 3670016  +Wv
constexpr int C4 = C3 + TC * TC / 4;   // 4718592  +Wo  -> 18432 blocks of 256
__global__ __launch_bounds__(256) void k_cvt5(
    const float* __restrict__ s0, const float* __restrict__ s1,
    const float* __restrict__ s2, const float* __restrict__ s3,
    const float* __restrict__ s4,
    __hip_bfloat16* __restrict__ d0, __hip_bfloat16* __restrict__ d1,
    __hip_bfloat16* __restrict__ d2, __hip_bfloat16* __restrict__ d3,
    __hip_bfloat16* __restrict__ d4) {
  int gid = blockIdx.x * 256 + threadIdx.x;
  const float* s;
  __hip_bfloat16* d;
  int base;
  if (gid < C1) {
    if (gid < C0) { s = s0; d = d0; base = 0; }
    else          { s = s1; d = d1; base = C0; }
  } else if (gid < C3) {
    if (gid < C2) { s = s2; d = d2; base = C1; }
    else          { s = s3; d = d3; base = C2; }
  } else            { s = s4; d = d4; base = C3; }
  int i = (gid - base) * 4;
  float4 v = *(const float4*)(s + i);
  ushort4 o;
  o.x = (unsigned short)bfbits(v.x);
  o.y = (unsigned short)bfbits(v.y);
  o.z = (unsigned short)bfbits(v.z);
  o.w = (unsigned short)bfbits(v.w);
  *(ushort4*)(d + i) = o;
}

// ---------- GEMM 128x128 (m97 + BK=64 + XOR swizzle) for GEMM2 ----------
template <typename OUT_T>
__global__ __launch_bounds__(256, 2) void k_gemm_bt(
    const __hip_bfloat16* __restrict__ A, const __hip_bfloat16* __restrict__ B,
    OUT_T* __restrict__ C, int M, int N, int K) {
  __shared__ __align__(16) __hip_bfloat16 As[128 * 64];  // 16 KB
  __shared__ __align__(16) __hip_bfloat16 Bs[128 * 64];  // 16 KB
  const int tid = threadIdx.x;
  const int lane = tid & 63, w = tid >> 6;
  const int q15 = lane & 15, quad = lane >> 4;
  const int wm = w >> 1, wn = w & 1;
  const int tm = blockIdx.y, tn = blockIdx.x;

  const int r0 = tid >> 3;
  const int csw = ((tid & 7) ^ (r0 & 7)) * 8;
  const __hip_bfloat16* ag = A + (size_t)(tm * 128 + r0) * K + csw;
  const __hip_bfloat16* bg = B + (size_t)(tn * 128 + r0) * K + csw;
  __hip_bfloat16* lA = As + (tid & ~63) * 8;  // wave-uniform base + lane*16B
  __hip_bfloat16* lB = Bs + (tid & ~63) * 8;

  floatx4 acc[4][4] = {};
  for (int k0 = 0; k0 < K; k0 += 64) {
    __syncthreads();
#pragma unroll
    for (int i = 0; i < 4; i++) {
      gl_lds16(ag + (size_t)(i * 32) * K + k0, lA + i * 2048);
      gl_lds16(bg + (size_t)(i * 32) * K + k0, lB + i * 2048);
    }
    __syncthreads();
#pragma unroll
    for (int kh = 0; kh < 2; kh++) {
      bf16x8 af[4], bfr[4];
#pragma unroll
      for (int i = 0; i < 4; i++)
        af[i] = *(const bf16x8*)(As + (wm * 64 + i * 16 + q15) * 64 +
                                 (((kh * 4 + quad) ^ (q15 & 7)) * 8));
#pragma unroll
      for (int i = 0; i < 4; i++)
        bfr[i] = *(const bf16x8*)(Bs + (wn * 64 + i * 16 + q15) * 64 +
                                  (((kh * 4 + quad) ^ (q15 & 7)) * 8));
#pragma unroll
      for (int mi = 0; mi < 4; mi++)
#pragma unroll
        for (int ni = 0; ni < 4; ni++)
          acc[mi][ni] = mfma16(af[mi], bfr[ni], acc[mi][ni]);
    }
  }
#pragma unroll
  for (int mi = 0; mi < 4; mi++) {
    int row0 = tm * 128 + wm * 64 + mi * 16 + quad * 4;
#pragma unroll
    for (int ni = 0; ni < 4; ni++) {
      int col = tn * 128 + wn * 64 + ni * 16 + q15;
#pragma unroll
      for (int r = 0; r < 4; r++)
        cstore(C + (size_t)(row0 + r) * N + col, acc[mi][ni][r]);
    }
  }
}

// ---------- GEMM1 fused: qkv-proj + RMSNorm + RoPE + V-transpose ----------
// (verified R10; eliminates qkv round-trip + k_prep launch, numerics
// bit-identical to the old path). R11 polish: V-transpose vectorized (8x
// fewer stores, 16B each) and RoPE trig via angle-addition recurrence
// (2 sincos + 4 FMA/row instead of 32 large-arg sincosf; drift ~2e-6).
__global__ __launch_bounds__(256, 2) void k_gemm_qkv(
    const __hip_bfloat16* __restrict__ A, const __hip_bfloat16* __restrict__ B,
    __hip_bfloat16* __restrict__ q_l, __hip_bfloat16* __restrict__ k_l,
    __hip_bfloat16* __restrict__ vt) {
  constexpr int K = TC;
  // union: K-loop uses [0,16384) as As/Bs; epilogue uses [0,16640) as tile
  __shared__ __align__(16) __hip_bfloat16 smem[128 * 130];  // 33.3 KB
  __hip_bfloat16* As = smem;
  __hip_bfloat16* Bs = smem + 128 * 64;
  const int tid = threadIdx.x;
  const int lane = tid & 63, w = tid >> 6;
  const int q15 = lane & 15, quad = lane >> 4;
  const int wm = w >> 1, wn = w & 1;
  const int tm = blockIdx.y, tn = blockIdx.x;

  const int r0 = tid >> 3;
  const int csw = ((tid & 7) ^ (r0 & 7)) * 8;
  const __hip_bfloat16* ag = A + (size_t)(tm * 128 + r0) * K + csw;
  const __hip_bfloat16* bg = B + (size_t)(tn * 128 + r0) * K + csw;
  __hip_bfloat16* lA = As + (tid & ~63) * 8;
  __hip_bfloat16* lB = Bs + (tid & ~63) * 8;

  floatx4 acc[4][4] = {};
  for (int k0 = 0; k0 < K; k0 += 64) {
    __syncthreads();
#pragma unroll
    for (int i = 0; i < 4; i++) {
      gl_lds16(ag + (size_t)(i * 32) * K + k0, lA + i * 2048);
      gl_lds16(bg + (size_t)(i * 32) * K + k0, lB + i * 2048);
    }
    __syncthreads();
#pragma unroll
    for (int kh = 0; kh < 2; kh++) {
      bf16x8 af[4], bfr[4];
#pragma unroll
      for (int i = 0; i < 4; i++)
        af[i] = *(const bf16x8*)(As + (wm * 64 + i * 16 + q15) * 64 +
                                 (((kh * 4 + quad) ^ (q15 & 7)) * 8));
#pragma unroll
      for (int i = 0; i < 4; i++)
        bfr[i] = *(const bf16x8*)(Bs + (wn * 64 + i * 16 + q15) * 64 +
                                  (((kh * 4 + quad) ^ (q15 & 7)) * 8));
#pragma unroll
      for (int mi = 0; mi < 4; mi++)
#pragma unroll
        for (int ni = 0; ni < 4; ni++)
          acc[mi][ni] = mfma16(af[mi], bfr[ni], acc[mi][ni]);
    }
  }

  // ---- epilogue: acc -> bf16 -> padded LDS tile [128 t][130] ----
  __syncthreads();  // all waves done reading As/Bs
#pragma unroll
  for (int mi = 0; mi < 4; mi++)
#pragma unroll
    for (int ni = 0; ni < 4; ni++) {
      int row = wm * 64 + mi * 16 + quad * 4;
      int col = wn * 64 + ni * 16 + q15;
#pragma unroll
      for (int r = 0; r < 4; r++)
        *(unsigned short*)(smem + (row + r) * 130 + col) =
            (unsigned short)bfbits(acc[mi][ni][r]);
    }
  __syncthreads();

  const int b = tm >> 4;  // batch of this 128-token row block
  if (tn < NH + NKV) {
    // Q head (tn<16) or K head: RMSNorm + RoPE, wave w covers rows w*32..+32
    const bool isq = tn < NH;
    const int h = isq ? tn : tn - NH;
    const float scale = isq ? (1.4426950408889634f * 0.08838834764831845f) : 1.0f;
    __hip_bfloat16* base = isq ? q_l + (size_t)(b * NH + h) * TT * HD
                               : k_l + (size_t)(b * NKV + h) * TT * HD;
    const float ifreq = exp2f((float)lane * -(13.287712379549449f / 64.0f));
    const int t0 = (tm & 15) * 128 + w * 32;
    // angle-addition recurrence: (cv,sv) = sincos((t0+j)*ifreq)
    float cv = cosf((float)t0 * ifreq), sv = sinf((float)t0 * ifreq);
    const float cF = cosf(ifreq), sF = sinf(ifreq);
    for (int j = 0; j < 32; ++j) {
      int row = w * 32 + j;
      int t = t0 + j;
      float x1 = __bfloat162float(smem[row * 130 + lane]);
      float x2 = __bfloat162float(smem[row * 130 + 64 + lane]);
      float ss = x1 * x1 + x2 * x2;
#pragma unroll
      for (int m = 1; m < 64; m <<= 1) ss += __shfl_xor(ss, m, 64);
      float rinv = rsqrtf(ss * (1.0f / 128.0f) + 1.1920928955078125e-07f);
      float o1 = (x1 * cv + x2 * sv) * rinv * scale;
      float o2 = (x2 * cv - x1 * sv) * rinv * scale;
      __hip_bfloat16* dst = base + (size_t)t * HD;
      *(unsigned short*)(dst + lane) = (unsigned short)bfbits(o1);
      *(unsigned short*)(dst + lane + 64) = (unsigned short)bfbits(o2);
      float cn = cv * cF - sv * sF;
      sv = sv * cF + cv * sF;
      cv = cn;
    }
  } else {
    // V head: transpose [128 t][128 d] -> vt[d][t], 16B vectorized stores.
    // Thread covers (d, tt0..tt0+7): 8 scalar LDS column reads -> one 16B store.
    const int hv = tn - NH - NKV;
    __hip_bfloat16* vbase = vt + (size_t)(b * NKV + hv) * HD * TT + (tm & 15) * 128;
#pragma unroll
    for (int j = 0; j < 8; ++j) {
      int e = j * 256 + tid;        // 0..2047 = 128 d x 16 tt-slots
      int d = e >> 4, tt0 = (e & 15) * 8;
      union { unsigned short u[8]; uint4 q; } pk;
#pragma unroll
      for (int i = 0; i < 8; ++i)
        pk.u[i] = *(const unsigned short*)(smem + (tt0 + i) * 130 + d);
      *(uint4*)(vbase + (size_t)d * TT + tt0) = pk.q;
    }
  }
}

// ---------- flash attention v8 (causal, GQA) ----------
// Verified local optimum (75.6 us, R10): 128-q tile, 4 waves, K/V dbuf gl_lds
// staging with XOR swizzle, in-register P transport via permlane swaps
// (bank conflicts = 0). R9 proved occupancy is NOT the limiter; the floor is
// the per-iteration serial chain.
__global__ __launch_bounds__(256, 2) void k_attn(
    const __hip_bfloat16* __restrict__ q_l, const __hip_bfloat16* __restrict__ k_l,
    const __hip_bfloat16* __restrict__ vt_l, __hip_bfloat16* __restrict__ y) {
  __shared__ __align__(16) __hip_bfloat16 Ks[2][64 * 128];   // 32 KB
  __shared__ __align__(16) __hip_bfloat16 Vs[2][128 * 64];   // 32 KB
  const int tid = threadIdx.x, lane = tid & 63, w = tid >> 6;
  const int q15 = lane & 15, quad = lane >> 4;
  const int id = blockIdx.x;
  const int sl = id >> 5;  // 16 slots of 32 blocks
  const int qt = (sl < 8) ? (15 - sl) : (sl - 8);  // pair-balanced mapping
  const int h = id & 15, b = (id >> 4) & 1;
  const int hk = h >> 2;
  const int nkb = 2 * qt + 2;

  const __hip_bfloat16* kbase = k_l + (size_t)(b * NKV + hk) * TT * HD;
  const __hip_bfloat16* vbase = vt_l + (size_t)(b * NKV + hk) * HD * TT;
  const __hip_bfloat16* qbase = q_l + ((size_t)(b * NH + h) * TT + qt * 128) * HD;

  auto stage = [&](int kb, int buf) {
#pragma unroll
    for (int i = 0; i < 4; i++) {
      int s = i * 256 + tid;
      int rk = s >> 4, ck = s & 15;
      gl_lds16(kbase + (size_t)(kb * 64 + rk) * HD + (ck ^ (rk & 15)) * 8,
               Ks[buf] + (i * 256 + (tid & ~63)) * 8);
      int rv = s >> 3, cv = s & 7;
      gl_lds16(vbase + (size_t)rv * TT + kb * 64 + (cv ^ (rv & 7)) * 8,
               Vs[buf] + (i * 256 + (tid & ~63)) * 8);
    }
  };

  // Q frags: wave covers q rows qt*128 + w*32 + qh*16 + q15
  bf16x8 qf[4][2];
#pragma unroll
  for (int dc = 0; dc < 4; dc++)
#pragma unroll
    for (int qh = 0; qh < 2; qh++)
      qf[dc][qh] = *(const bf16x8*)(qbase + (size_t)(w * 32 + qh * 16 + q15) * HD +
                                    dc * 32 + quad * 8);

  floatx4 ot[8][2] = {};
  float lsum[2] = {0.0f, 0.0f};
  int cur = 0;
  const int kb_last_w = 2 * qt + (w >> 1);  // waves 0,1 skip final all-masked iter

  for (int kb = 0; kb < nkb; kb++) {
    __syncthreads();
    if (kb == 0) {
      stage(0, cur);
      __syncthreads();
    }
    if (kb + 1 < nkb) stage(kb + 1, cur ^ 1);

    if (kb <= kb_last_w) {
      // S^T = K @ Q^T : [64 k][32 q] as two 16-col C-tiles per kt
      floatx4 st[4][2] = {};
#pragma unroll
      for (int kt = 0; kt < 4; kt++) {
        int r = kt * 16 + q15;
#pragma unroll
        for (int dc = 0; dc < 4; dc++) {
          int c = dc * 4 + quad;
          bf16x8 kf = *(const bf16x8*)(Ks[cur] + (r * 16 + (c ^ (r & 15))) * 8);
          st[kt][0] = mfma16(kf, qf[dc][0], st[kt][0]);
          st[kt][1] = mfma16(kf, qf[dc][1], st[kt][1]);
        }
      }
      if (kb >= 2 * qt) {  // causal mask (diagonal region)
#pragma unroll
        for (int qh = 0; qh < 2; qh++) {
          int qg = qt * 128 + w * 32 + qh * 16 + q15;
#pragma unroll
          for (int kt = 0; kt < 4; kt++)
#pragma unroll
            for (int r = 0; r < 4; r++)
              if (kb * 64 + kt * 16 + quad * 4 + r > qg) st[kt][qh][r] = -INFINITY;
        }
      }
      // static-max softmax: p = exp2(s); pack P into per-kt dwords (C layout)
      int pA[2][4], pB[2][4];
#pragma unroll
      for (int kt = 0; kt < 4; kt++) {
#pragma unroll
        for (int qh = 0; qh < 2; qh++) {
          float p0 = exp2f(st[kt][qh][0]);
          float p1 = exp2f(st[kt][qh][1]);
          float p2 = exp2f(st[kt][qh][2]);
          float p3 = exp2f(st[kt][qh][3]);
          lsum[qh] += (p0 + p1) + (p2 + p3);
          pA[qh][kt] = pk2(p0, p1);
          pB[qh][kt] = pk2(p2, p3);
        }
      }
      // PV: y^T[128 d][32 q] += V^T @ P^T ; P B-frags via permlane swaps
#pragma unroll
      for (int kc = 0; kc < 2; kc++) {
        bf16x8 pf[2];
#pragma unroll
        for (int qh = 0; qh < 2; qh++) {
          int u0 = pA[qh][2 * kc], u1 = pA[qh][2 * kc + 1];
          int v0 = pB[qh][2 * kc], v1 = pB[qh][2 * kc + 1];
          asm("v_permlane32_swap_b32 %0, %1" : "+v"(u0), "+v"(u1));
          asm("v_permlane16_swap_b32 %0, %1" : "+v"(u0), "+v"(u1));
          asm("v_permlane32_swap_b32 %0, %1" : "+v"(v0), "+v"(v1));
          asm("v_permlane16_swap_b32 %0, %1" : "+v"(v0), "+v"(v1));
          intx4 wi;
          wi[0] = u0; wi[1] = v0; wi[2] = u1; wi[3] = v1;
          pf[qh] = __builtin_bit_cast(bf16x8, wi);
        }
#pragma unroll
        for (int dt = 0; dt < 8; dt++) {
          int r = dt * 16 + q15, c = kc * 4 + quad;
          bf16x8 vf = *(const bf16x8*)(Vs[cur] + (r * 8 + (c ^ (r & 7))) * 8);
          ot[dt][0] = mfma16(vf, pf[0], ot[dt][0]);
          ot[dt][1] = mfma16(vf, pf[1], ot[dt][1]);
        }
      }
    }
    cur ^= 1;
  }
  // epilogue: reduce l across quads, normalize, store y[b][t][h*128+d]
#pragma unroll
  for (int qh = 0; qh < 2; qh++) {
    float ls = lsum[qh];
    ls += __shfl_xor(ls, 16, 64);
    ls += __shfl_xor(ls, 32, 64);
    float linv = 1.0f / ls;
    int t = qt * 128 + w * 32 + qh * 16 + q15;
    __hip_bfloat16* yrow = y + (size_t)(b * TT + t) * TC + h * HD;
#pragma unroll
    for (int dt = 0; dt < 8; dt++) {
      int d = dt * 16 + quad * 4;
      ushort4 o;
      o.x = (unsigned short)bfbits(ot[dt][qh][0] * linv);
      o.y = (unsigned short)bfbits(ot[dt][qh][1] * linv);
      o.z = (unsigned short)bfbits(ot[dt][qh][2] * linv);
      o.w = (unsigned short)bfbits(ot[dt][qh][3] * linv);
      *(ushort4*)(yrow + d) = o;
    }
  }
}

// ---------- launcher ----------
extern "C" void kernel_launch(void* const* d_in, const int* in_sizes, int n_in,
                              void* d_out, int out_size, void* d_ws, size_t ws_size,
                              hipStream_t stream) {
  (void)in_sizes; (void)n_in; (void)out_size; (void)ws_size;
  const float* x  = (const float*)d_in[0];
  const float* Wq = (const float*)d_in[1];
  const float* Wk = (const float*)d_in[2];
  const float* Wv = (const float*)d_in[3];
  const float* Wo = (const float*)d_in[4];
  float* out = (float*)d_out;

  char* ws = (char*)d_ws;
  size_t off = 0;
  auto alloc = [&](size_t bytes) {
    void* p = ws + off;
    off += (bytes + 255) & ~(size_t)255;
    return p;
  };
  __hip_bfloat16* xb   = (__hip_bfloat16*)alloc((size_t)MR * TC * 2);
  __hip_bfloat16* wqkv = (__hip_bfloat16*)alloc((size_t)NQKV * TC * 2);
  __hip_bfloat16* wo   = (__hip_bfloat16*)alloc((size_t)TC * TC * 2);
  __hip_bfloat16* q_l  = (__hip_bfloat16*)alloc((size_t)TB * NH * TT * HD * 2);
  __hip_bfloat16* k_l  = (__hip_bfloat16*)alloc((size_t)TB * NKV * TT * HD * 2);
  __hip_bfloat16* vt_l = (__hip_bfloat16*)alloc((size_t)TB * NKV * HD * TT * 2);
  __hip_bfloat16* yb   = (__hip_bfloat16*)alloc((size_t)MR * TC * 2);

  // exact grid: 4718592 vec4 / 256 = 18432 blocks (was 40960 with 55% empty)
  k_cvt5<<<C4 / 256, 256, 0, stream>>>(
      x, Wq, Wk, Wv, Wo,
      xb, wqkv, wqkv + (size_t)NQ * TC, wqkv + (size_t)(NQ + NK) * TC, wo);

  // GEMM1 fused with RMSNorm+RoPE+V-transpose: grid 24x32, replaces k_prep
  k_gemm_qkv<<<dim3(NQKV / 128, MR / 128), 256, 0, stream>>>(
      xb, wqkv, q_l, k_l, vt_l);

  // flash attention: 16 q-tiles x 16 heads x 2 batch = 512 blocks
  k_attn<<<(TT / 128) * NH * TB, 256, 0, stream>>>(q_l, k_l, vt_l, yb);

  // GEMM2: 4096x2048x2048, 128^2 BK=64+swizzle, grid 16x32 = 512 blocks
  k_gemm_bt<float><<<dim3(TC / 128, MR / 128), 256, 0, stream>>>(
      yb, wo, out, MR, TC, TC);
}